// Round 1
// baseline (1315.904 us; speedup 1.0000x reference)
//
#include <hip/hip_runtime.h>

// QuantLinear W4A32 fused dequant-GEMM for gfx950.
// M=4096 (B*S), K=4096, N=11008, GROUP=128, 4-bit weights packed 8/int32 along K,
// zeros packed 8/int32 along N.
// Structure: 128x128 block tile, BK=32, 4 waves (2x2), mfma_f32_16x16x32_bf16,
// fp32 accum. A: fp32->bf16 during staging. B: inline dequant into Bs[n][k].

#define BM 128
#define BN 128
#define BK 32
#define LDK 40  // padded LDS stride in shorts: 80B row stride, 16B-aligned, 2-way banks max

typedef __bf16 v8bf __attribute__((ext_vector_type(8)));
typedef float v4f __attribute__((ext_vector_type(4)));
typedef short v8s __attribute__((ext_vector_type(8)));
typedef short v4s __attribute__((ext_vector_type(4)));

__device__ __forceinline__ short f2bf(float f) {
  // round-to-nearest-even fp32 -> bf16 (no NaN handling needed: inputs finite)
  unsigned u = __builtin_bit_cast(unsigned, f);
  u += 0x7fffu + ((u >> 16) & 1u);
  return (short)(u >> 16);
}

__global__ __launch_bounds__(256, 2)
void qgemm_fused(const float* __restrict__ x,
                 const unsigned* __restrict__ qweight,
                 const unsigned* __restrict__ qzeros,
                 const float* __restrict__ scales,
                 float* __restrict__ out,
                 int M, int N, int K) {
  __shared__ short As[BM][LDK];  // As[m][k]  (bf16 bits)
  __shared__ short Bs[BN][LDK];  // Bs[n][k]  (W^T tile, bf16 bits)

  const int tid = threadIdx.x;
  const int lane = tid & 63;
  const int wid = tid >> 6;           // 4 waves
  const int n0 = blockIdx.x * BN;
  const int m0 = blockIdx.y * BM;
  const int wm = (wid >> 1) * 64;     // wave row offset in tile
  const int wn = (wid & 1) * 64;      // wave col offset in tile
  const int lr = lane & 15;           // row/col within 16x16 frag
  const int lk = (lane >> 4) * 8;     // k offset within frag: 0,8,16,24

  // A staging: 4 passes x 32 rows; thread -> row tid/8, k-chunk (tid%8)*4
  const int a_row = tid >> 3;
  const int a_col = (tid & 7) * 4;
  // B staging: thread -> n = tid&127, krows {tid>>7, tid>>7 + 2}
  const int b_n = tid & 127;
  const int b_kr0 = tid >> 7;
  const int gn = n0 + b_n;

  v4f acc[4][4] = {};  // 64 AGPRs

  const int ngroups = K / 128;
  for (int g = 0; g < ngroups; ++g) {
    // group-uniform dequant params for this thread's column gn
    const unsigned zpack = qzeros[(size_t)g * (N >> 3) + (gn >> 3)];
    const float s = scales[(size_t)g * N + gn];
    const float nzs = -s * (float)((zpack >> ((gn & 7) * 4)) & 15u);

    for (int t = 0; t < 128 / BK; ++t) {
      const int kk = g * 128 + t * BK;

      // ---- stage A: x fp32 -> bf16 into As[m][k] ----
      #pragma unroll
      for (int p = 0; p < 4; ++p) {
        const int row = p * 32 + a_row;
        const float4 v = *(const float4*)(x + (size_t)(m0 + row) * K + kk + a_col);
        v4s pv;
        pv.x = f2bf(v.x);
        pv.y = f2bf(v.y);
        pv.z = f2bf(v.z);
        pv.w = f2bf(v.w);
        *(v4s*)(&As[row][a_col]) = pv;  // 8B ds_write
      }

      // ---- stage B: dequant 4-bit -> bf16 into Bs[n][k] ----
      #pragma unroll
      for (int q = 0; q < 2; ++q) {
        const int kr = b_kr0 + q * 2;  // 0..3 (k-rows of packed qweight)
        const unsigned qv = qweight[(size_t)((kk >> 3) + kr) * N + gn];
        v8s wv;
        #pragma unroll
        for (int i = 0; i < 8; ++i) {
          const float f = fmaf((float)((qv >> (4 * i)) & 15u), s, nzs);
          wv[i] = f2bf(f);
        }
        *(v8s*)(&Bs[b_n][kr * 8]) = wv;  // 16B ds_write, 16B-aligned
      }

      __syncthreads();

      // ---- fragments + MFMA ----
      v8bf af[4], bfr[4];
      #pragma unroll
      for (int i = 0; i < 4; ++i) {
        af[i] = *(const v8bf*)(&As[wm + i * 16 + lr][lk]);   // ds_read_b128
        bfr[i] = *(const v8bf*)(&Bs[wn + i * 16 + lr][lk]);  // ds_read_b128
      }
      #pragma unroll
      for (int mi = 0; mi < 4; ++mi) {
        #pragma unroll
        for (int ni = 0; ni < 4; ++ni) {
          acc[mi][ni] = __builtin_amdgcn_mfma_f32_16x16x32_bf16(
              af[mi], bfr[ni], acc[mi][ni], 0, 0, 0);
        }
      }

      __syncthreads();
    }
  }

  // ---- epilogue: C/D layout col=lane&15, row=(lane>>4)*4+reg ----
  #pragma unroll
  for (int mi = 0; mi < 4; ++mi) {
    #pragma unroll
    for (int ni = 0; ni < 4; ++ni) {
      #pragma unroll
      for (int r = 0; r < 4; ++r) {
        const int row = m0 + wm + mi * 16 + (lane >> 4) * 4 + r;
        const int col = n0 + wn + ni * 16 + lr;
        out[(size_t)row * N + col] = acc[mi][ni][r];
      }
    }
  }
}

extern "C" void kernel_launch(void* const* d_in, const int* in_sizes, int n_in,
                              void* d_out, int out_size, void* d_ws, size_t ws_size,
                              hipStream_t stream) {
  const float* x = (const float*)d_in[0];
  const unsigned* qweight = (const unsigned*)d_in[1];
  const unsigned* qzeros = (const unsigned*)d_in[2];
  const float* scales = (const float*)d_in[3];
  float* out = (float*)d_out;

  const int K = 4096;
  const int N = 11008;
  const int M = in_sizes[0] / K;  // B*S = 4096

  dim3 grid(N / BN, M / BM);  // 86 x 32
  qgemm_fused<<<grid, 256, 0, stream>>>(x, qweight, qzeros, scales, out, M, N, K);
}

// Round 3
// 752.699 us; speedup vs baseline: 1.7482x; 1.7482x over previous
//
#include <hip/hip_runtime.h>

// QuantLinear W4A32 fused dequant-GEMM for gfx950 — round 2b (compile fix).
// * f16 MFMA (mfma_f32_16x16x32_f16) — cheap packed dequant (fp16 magic trick)
//   and cvt_pkrtz for A staging.
// * software pipeline: step t+1's global loads issued during step t's MFMA.
// Structure: 128x128 tile, BK=32, 4 waves (2x2), fp32 accum, 2-barrier K-loop.

#define BM 128
#define BN 128
#define BK 32
#define LDK 40  // padded LDS stride in shorts: 80B row stride, 16B-aligned

typedef _Float16 v8h __attribute__((ext_vector_type(8)));
typedef _Float16 half2v __attribute__((ext_vector_type(2)));
typedef float v4f __attribute__((ext_vector_type(4)));

__device__ __forceinline__ unsigned pkrtz_u32(float a, float b) {
  // fp32x2 -> packed f16x2 (round-toward-zero), as raw u32 bits
  return __builtin_bit_cast(unsigned, __builtin_amdgcn_cvt_pkrtz(a, b));
}

__global__ __launch_bounds__(256, 2)
void qgemm_fused(const float* __restrict__ x,
                 const unsigned* __restrict__ qweight,
                 const unsigned* __restrict__ qzeros,
                 const float* __restrict__ scales,
                 float* __restrict__ out,
                 int M, int N, int K) {
  __shared__ short As[BM][LDK];  // As[m][k]  (f16 bits)
  __shared__ short Bs[BN][LDK];  // Bs[n][k]  (W^T tile, f16 bits)

  const int tid = threadIdx.x;
  const int lane = tid & 63;
  const int wid = tid >> 6;
  const int n0 = blockIdx.x * BN;
  const int m0 = blockIdx.y * BM;
  const int wm = (wid >> 1) * 64;
  const int wn = (wid & 1) * 64;
  const int lr = lane & 15;
  const int lk = (lane >> 4) * 8;

  // A staging: thread -> row tid/8 (+p*32), k-chunk (tid%8)*4
  const int a_row = tid >> 3;
  const int a_col = (tid & 7) * 4;
  // B staging: thread -> n = tid&127, k-rows {tid>>7, tid>>7+2}
  const int b_n = tid & 127;
  const int b_kr0 = tid >> 7;
  const int gn = n0 + b_n;

  const float* xb = x + (size_t)(m0 + a_row) * K + a_col;
  const unsigned* qwb = qweight + (size_t)b_kr0 * N + gn;

  v4f acc[4][4] = {};

  const int NT = K / BK;  // 128 steps

  // ---- prefetch state ----
  float4 axc[4];
  unsigned b0c, b1c, zpc;
  float scc;

  auto load_step = [&](int t, float4 ax[4], unsigned& b0, unsigned& b1,
                       unsigned& zp, float& sc) {
    const int kk = t * BK;
#pragma unroll
    for (int p = 0; p < 4; ++p)
      ax[p] = *(const float4*)(xb + (size_t)(p * 32) * K + kk);
    const size_t qoff = (size_t)(kk >> 3) * N;
    b0 = qwb[qoff];
    b1 = qwb[qoff + 2 * (size_t)N];
    const int g = kk >> 7;
    zp = qzeros[(size_t)g * (N >> 3) + (gn >> 3)];
    sc = scales[(size_t)g * N + gn];
  };

  load_step(0, axc, b0c, b1c, zpc, scc);

#pragma unroll 2
  for (int t = 0; t < NT; ++t) {
    // ---- group dequant constants from prefetched params ----
    const unsigned z = (zpc >> ((gn & 7) * 4)) & 15u;
    const unsigned hz_u = 0x64006400u | z | (z << 16);
    const half2v hz2 = __builtin_bit_cast(half2v, hz_u);
    const half2v hs2 = __builtin_bit_cast(half2v, pkrtz_u32(scc, scc));

    // ---- stage A: fp32 -> f16 (pkrtz) into As[m][k] ----
#pragma unroll
    for (int p = 0; p < 4; ++p) {
      const int row = p * 32 + a_row;
      uint2 pv;
      pv.x = pkrtz_u32(axc[p].x, axc[p].y);
      pv.y = pkrtz_u32(axc[p].z, axc[p].w);
      *(uint2*)(&As[row][a_col]) = pv;  // 8B ds_write
    }

    // ---- stage B: 4-bit -> f16 dequant (magic trick) into Bs[n][k] ----
    {
      const unsigned qvs[2] = {b0c, b1c};
#pragma unroll
      for (int q = 0; q < 2; ++q) {
        const int kr = b_kr0 + q * 2;
        const unsigned qv = qvs[q];
        uint4 wv;
        unsigned* wp = (unsigned*)&wv;
#pragma unroll
        for (int j = 0; j < 4; ++j) {
          const unsigned byte = qv >> (8 * j);
          const unsigned pq = 0x64006400u | (byte & 0xFu) | ((byte & 0xF0u) << 12);
          const half2v w2 = (__builtin_bit_cast(half2v, pq) - hz2) * hs2;
          wp[j] = __builtin_bit_cast(unsigned, w2);
        }
        *(uint4*)(&Bs[b_n][kr * 8]) = wv;  // 16B ds_write
      }
    }

    __syncthreads();

    // ---- prefetch next step (overlaps MFMA phase) ----
    float4 axn[4];
    unsigned b0n, b1n, zpn;
    float scn;
    const int tn = (t + 1 < NT) ? (t + 1) : t;  // last iter: redundant reload
    load_step(tn, axn, b0n, b1n, zpn, scn);

    // ---- fragments + MFMA ----
    v8h af[4], bfr[4];
#pragma unroll
    for (int i = 0; i < 4; ++i) {
      af[i] = *(const v8h*)(&As[wm + i * 16 + lr][lk]);   // ds_read_b128
      bfr[i] = *(const v8h*)(&Bs[wn + i * 16 + lr][lk]);  // ds_read_b128
    }
#pragma unroll
    for (int mi = 0; mi < 4; ++mi) {
#pragma unroll
      for (int ni = 0; ni < 4; ++ni) {
        acc[mi][ni] = __builtin_amdgcn_mfma_f32_16x16x32_f16(
            af[mi], bfr[ni], acc[mi][ni], 0, 0, 0);
      }
    }

    __syncthreads();

    // rotate prefetch regs
#pragma unroll
    for (int p = 0; p < 4; ++p) axc[p] = axn[p];
    b0c = b0n; b1c = b1n; zpc = zpn; scc = scn;
  }

  // ---- epilogue: C/D layout col=lane&15, row=(lane>>4)*4+reg ----
#pragma unroll
  for (int mi = 0; mi < 4; ++mi) {
#pragma unroll
    for (int ni = 0; ni < 4; ++ni) {
#pragma unroll
      for (int r = 0; r < 4; ++r) {
        const int row = m0 + wm + mi * 16 + (lane >> 4) * 4 + r;
        const int col = n0 + wn + ni * 16 + lr;
        out[(size_t)row * N + col] = acc[mi][ni][r];
      }
    }
  }
}

extern "C" void kernel_launch(void* const* d_in, const int* in_sizes, int n_in,
                              void* d_out, int out_size, void* d_ws, size_t ws_size,
                              hipStream_t stream) {
  const float* x = (const float*)d_in[0];
  const unsigned* qweight = (const unsigned*)d_in[1];
  const unsigned* qzeros = (const unsigned*)d_in[2];
  const float* scales = (const float*)d_in[3];
  float* out = (float*)d_out;

  const int K = 4096;
  const int N = 11008;
  const int M = in_sizes[0] / K;  // B*S = 4096

  dim3 grid(N / BN, M / BM);  // 86 x 32
  qgemm_fused<<<grid, 256, 0, stream>>>(x, qweight, qzeros, scales, out, M, N, K);
}

// Round 4
// 665.894 us; speedup vs baseline: 1.9761x; 1.1304x over previous
//
#include <hip/hip_runtime.h>

// QuantLinear W4A32 fused dequant-GEMM for gfx950 — round 4.
//  * prep_x: x fp32 -> f16, stored in tile-padded layout (128x40-half tiles,
//    10240B) in workspace; main kernel stages A via global_load_lds (DMA,
//    zero VALU) because global tile layout == LDS layout.
//  * main tile 128x256, 512 threads (2x4 waves of 64x64), BK=32.
//  * B: fused 4-bit -> f16 magic-trick dequant, register-prefetched 1 step.
// Fallback (ws too small): round-3 fused kernel (128x128).

#define BK 32
#define LDK 40            // padded LDS/global row stride in halves (80B)
#define TILE_BYTES 10240  // 128 * LDK * 2

typedef _Float16 v8h __attribute__((ext_vector_type(8)));
typedef _Float16 half2v __attribute__((ext_vector_type(2)));
typedef float v4f __attribute__((ext_vector_type(4)));

__device__ __forceinline__ unsigned pkrtz_u32(float a, float b) {
  return __builtin_bit_cast(unsigned, __builtin_amdgcn_cvt_pkrtz(a, b));
}

__device__ __forceinline__ void load_lds_16B(const void* g, void* l) {
  __builtin_amdgcn_global_load_lds(
      (const __attribute__((address_space(1))) unsigned*)g,
      (__attribute__((address_space(3))) unsigned*)l, 16, 0, 0);
}

// ---------------- prep: x fp32 -> f16 tiled-padded ----------------
// grid (K/32, M/128), 256 threads. Tile (mt,kt): 128 rows x LDK halves,
// rows 0..31 hold data, cols 32..39 padding (never read).
__global__ __launch_bounds__(256)
void prep_x(const float* __restrict__ x, unsigned short* __restrict__ xt, int K) {
  const int kt = blockIdx.x, mt = blockIdx.y;
  const int t = threadIdx.x;
  const int row = t >> 1, half = t & 1;
  const float* src = x + (size_t)(mt * 128 + row) * K + kt * 32 + half * 16;
  const float4 v0 = ((const float4*)src)[0];
  const float4 v1 = ((const float4*)src)[1];
  const float4 v2 = ((const float4*)src)[2];
  const float4 v3 = ((const float4*)src)[3];
  uint4 o0, o1;
  o0.x = pkrtz_u32(v0.x, v0.y); o0.y = pkrtz_u32(v0.z, v0.w);
  o0.z = pkrtz_u32(v1.x, v1.y); o0.w = pkrtz_u32(v1.z, v1.w);
  o1.x = pkrtz_u32(v2.x, v2.y); o1.y = pkrtz_u32(v2.z, v2.w);
  o1.z = pkrtz_u32(v3.x, v3.y); o1.w = pkrtz_u32(v3.z, v3.w);
  unsigned short* dst =
      xt + (size_t)(mt * (K / 32) + kt) * (TILE_BYTES / 2) + row * LDK + half * 16;
  ((uint4*)dst)[0] = o0;
  ((uint4*)(dst + 8))[0] = o1;
}

// ---------------- main: 128x256 tile, A via DMA, B fused dequant ----------------
__global__ __launch_bounds__(512, 4)
void qgemm_dma(const unsigned short* __restrict__ xt,
               const unsigned* __restrict__ qweight,
               const unsigned* __restrict__ qzeros,
               const float* __restrict__ scales,
               float* __restrict__ out,
               int M, int N, int K) {
  __shared__ __align__(16) short As[128][LDK];  // f16 bits, filled by DMA
  __shared__ __align__(16) short Bs[256][LDK];  // f16 bits, fused dequant

  const int tid = threadIdx.x;
  const int lane = tid & 63;
  const int wid = tid >> 6;            // 8 waves
  const int n0 = blockIdx.x * 256;
  const int m0 = blockIdx.y * 128;
  const int mt = blockIdx.y;
  const int wm = (wid >> 2) * 64;      // 2 wave-rows
  const int wn = (wid & 3) * 64;       // 4 wave-cols
  const int lr = lane & 15;
  const int lk = (lane >> 4) * 8;

  // B staging: n = tid&255, k-rows {tid>>8, tid>>8 + 2}
  const int b_n = tid & 255;
  const int b_kr0 = tid >> 8;
  const int gn = n0 + b_n;
  const unsigned* qwb = qweight + (size_t)b_kr0 * N + gn;

  const char* xt_b = (const char*)xt;
  const int NT = K / BK;  // 128 steps

  v4f acc[4][4] = {};

  // ---- B prefetch state ----
  unsigned b0c, b1c, zpc;
  float scc;
  auto load_b = [&](int t, unsigned& b0, unsigned& b1, unsigned& zp, float& sc) {
    const int kk = t * BK;
    const size_t qoff = (size_t)(kk >> 3) * N;
    b0 = qwb[qoff];
    b1 = qwb[qoff + 2 * (size_t)N];
    const int g = kk >> 7;
    zp = qzeros[(size_t)g * (N >> 3) + (gn >> 3)];
    sc = scales[(size_t)g * N + gn];
  };
  load_b(0, b0c, b1c, zpc, scc);

#pragma unroll 2
  for (int t = 0; t < NT; ++t) {
    // ---- A: async DMA global tile -> LDS (10 x 1KB wave-chunks) ----
    {
      const char* g = xt_b + (size_t)(mt * NT + t) * TILE_BYTES +
                      (size_t)wid * 1024 + (size_t)lane * 16;
      char* l = ((char*)&As[0][0]) + wid * 1024;
      load_lds_16B(g, l);
      if (wid < 2) load_lds_16B(g + 8 * 1024, l + 8 * 1024);
    }

    // ---- B: 4-bit -> f16 dequant (magic trick) into Bs[n][k] ----
    {
      const unsigned z = (zpc >> ((gn & 7) * 4)) & 15u;
      const unsigned hz_u = 0x64006400u | z | (z << 16);
      const half2v hz2 = __builtin_bit_cast(half2v, hz_u);
      const half2v hs2 = __builtin_bit_cast(half2v, pkrtz_u32(scc, scc));
      const unsigned qvs[2] = {b0c, b1c};
#pragma unroll
      for (int q = 0; q < 2; ++q) {
        const int kr = b_kr0 + q * 2;
        const unsigned qv = qvs[q];
        uint4 wv;
        unsigned* wp = (unsigned*)&wv;
#pragma unroll
        for (int j = 0; j < 4; ++j) {
          const unsigned byte = qv >> (8 * j);
          const unsigned pq = 0x64006400u | (byte & 0xFu) | ((byte & 0xF0u) << 12);
          const half2v w2 = (__builtin_bit_cast(half2v, pq) - hz2) * hs2;
          wp[j] = __builtin_bit_cast(unsigned, w2);
        }
        *(uint4*)(&Bs[b_n][kr * 8]) = wv;  // 16B ds_write
      }
    }

    __syncthreads();  // drains A-DMA (vmcnt) + B ds_writes

    // ---- prefetch next step's B (overlaps MFMA phase) ----
    unsigned b0n, b1n, zpn;
    float scn;
    const int tn = (t + 1 < NT) ? (t + 1) : t;
    load_b(tn, b0n, b1n, zpn, scn);

    // ---- fragments + MFMA ----
    v8h af[4], bfr[4];
#pragma unroll
    for (int i = 0; i < 4; ++i) {
      af[i] = *(const v8h*)(&As[wm + i * 16 + lr][lk]);   // ds_read_b128
      bfr[i] = *(const v8h*)(&Bs[wn + i * 16 + lr][lk]);  // ds_read_b128
    }
#pragma unroll
    for (int mi = 0; mi < 4; ++mi) {
#pragma unroll
      for (int ni = 0; ni < 4; ++ni) {
        acc[mi][ni] = __builtin_amdgcn_mfma_f32_16x16x32_f16(
            af[mi], bfr[ni], acc[mi][ni], 0, 0, 0);
      }
    }

    __syncthreads();

    b0c = b0n; b1c = b1n; zpc = zpn; scc = scn;
  }

  // ---- epilogue: C/D layout col=lane&15, row=(lane>>4)*4+reg ----
#pragma unroll
  for (int mi = 0; mi < 4; ++mi) {
#pragma unroll
    for (int ni = 0; ni < 4; ++ni) {
#pragma unroll
      for (int r = 0; r < 4; ++r) {
        const int row = m0 + wm + mi * 16 + (lane >> 4) * 4 + r;
        const int col = n0 + wn + ni * 16 + lr;
        out[(size_t)row * N + col] = acc[mi][ni][r];
      }
    }
  }
}

// ---------------- fallback: round-3 fused kernel (128x128) ----------------
__global__ __launch_bounds__(256, 2)
void qgemm_fused(const float* __restrict__ x,
                 const unsigned* __restrict__ qweight,
                 const unsigned* __restrict__ qzeros,
                 const float* __restrict__ scales,
                 float* __restrict__ out,
                 int M, int N, int K) {
  __shared__ short As[128][LDK];
  __shared__ short Bs[128][LDK];

  const int tid = threadIdx.x;
  const int lane = tid & 63;
  const int wid = tid >> 6;
  const int n0 = blockIdx.x * 128;
  const int m0 = blockIdx.y * 128;
  const int wm = (wid >> 1) * 64;
  const int wn = (wid & 1) * 64;
  const int lr = lane & 15;
  const int lk = (lane >> 4) * 8;

  const int a_row = tid >> 3;
  const int a_col = (tid & 7) * 4;
  const int b_n = tid & 127;
  const int b_kr0 = tid >> 7;
  const int gn = n0 + b_n;

  const float* xb = x + (size_t)(m0 + a_row) * K + a_col;
  const unsigned* qwb = qweight + (size_t)b_kr0 * N + gn;

  v4f acc[4][4] = {};
  const int NT = K / BK;

  float4 axc[4];
  unsigned b0c, b1c, zpc;
  float scc;

  auto load_step = [&](int t, float4 ax[4], unsigned& b0, unsigned& b1,
                       unsigned& zp, float& sc) {
    const int kk = t * BK;
#pragma unroll
    for (int p = 0; p < 4; ++p)
      ax[p] = *(const float4*)(xb + (size_t)(p * 32) * K + kk);
    const size_t qoff = (size_t)(kk >> 3) * N;
    b0 = qwb[qoff];
    b1 = qwb[qoff + 2 * (size_t)N];
    const int g = kk >> 7;
    zp = qzeros[(size_t)g * (N >> 3) + (gn >> 3)];
    sc = scales[(size_t)g * N + gn];
  };

  load_step(0, axc, b0c, b1c, zpc, scc);

#pragma unroll 2
  for (int t = 0; t < NT; ++t) {
    const unsigned z = (zpc >> ((gn & 7) * 4)) & 15u;
    const unsigned hz_u = 0x64006400u | z | (z << 16);
    const half2v hz2 = __builtin_bit_cast(half2v, hz_u);
    const half2v hs2 = __builtin_bit_cast(half2v, pkrtz_u32(scc, scc));

#pragma unroll
    for (int p = 0; p < 4; ++p) {
      const int row = p * 32 + a_row;
      uint2 pv;
      pv.x = pkrtz_u32(axc[p].x, axc[p].y);
      pv.y = pkrtz_u32(axc[p].z, axc[p].w);
      *(uint2*)(&As[row][a_col]) = pv;
    }
    {
      const unsigned qvs[2] = {b0c, b1c};
#pragma unroll
      for (int q = 0; q < 2; ++q) {
        const int kr = b_kr0 + q * 2;
        const unsigned qv = qvs[q];
        uint4 wv;
        unsigned* wp = (unsigned*)&wv;
#pragma unroll
        for (int j = 0; j < 4; ++j) {
          const unsigned byte = qv >> (8 * j);
          const unsigned pq = 0x64006400u | (byte & 0xFu) | ((byte & 0xF0u) << 12);
          const half2v w2 = (__builtin_bit_cast(half2v, pq) - hz2) * hs2;
          wp[j] = __builtin_bit_cast(unsigned, w2);
        }
        *(uint4*)(&Bs[b_n][kr * 8]) = wv;
      }
    }

    __syncthreads();

    float4 axn[4];
    unsigned b0n, b1n, zpn;
    float scn;
    const int tn = (t + 1 < NT) ? (t + 1) : t;
    load_step(tn, axn, b0n, b1n, zpn, scn);

    v8h af[4], bfr[4];
#pragma unroll
    for (int i = 0; i < 4; ++i) {
      af[i] = *(const v8h*)(&As[wm + i * 16 + lr][lk]);
      bfr[i] = *(const v8h*)(&Bs[wn + i * 16 + lr][lk]);
    }
#pragma unroll
    for (int mi = 0; mi < 4; ++mi) {
#pragma unroll
      for (int ni = 0; ni < 4; ++ni) {
        acc[mi][ni] = __builtin_amdgcn_mfma_f32_16x16x32_f16(
            af[mi], bfr[ni], acc[mi][ni], 0, 0, 0);
      }
    }

    __syncthreads();

#pragma unroll
    for (int p = 0; p < 4; ++p) axc[p] = axn[p];
    b0c = b0n; b1c = b1n; zpc = zpn; scc = scn;
  }

#pragma unroll
  for (int mi = 0; mi < 4; ++mi) {
#pragma unroll
    for (int ni = 0; ni < 4; ++ni) {
#pragma unroll
      for (int r = 0; r < 4; ++r) {
        const int row = m0 + wm + mi * 16 + (lane >> 4) * 4 + r;
        const int col = n0 + wn + ni * 16 + lr;
        out[(size_t)row * N + col] = acc[mi][ni][r];
      }
    }
  }
}

extern "C" void kernel_launch(void* const* d_in, const int* in_sizes, int n_in,
                              void* d_out, int out_size, void* d_ws, size_t ws_size,
                              hipStream_t stream) {
  const float* x = (const float*)d_in[0];
  const unsigned* qweight = (const unsigned*)d_in[1];
  const unsigned* qzeros = (const unsigned*)d_in[2];
  const float* scales = (const float*)d_in[3];
  float* out = (float*)d_out;

  const int K = 4096;
  const int N = 11008;
  const int M = in_sizes[0] / K;  // 4096

  const size_t need = (size_t)(M / 128) * (K / 32) * TILE_BYTES;  // 41.9 MB
  if (ws_size >= need) {
    unsigned short* xt = (unsigned short*)d_ws;
    prep_x<<<dim3(K / 32, M / 128), 256, 0, stream>>>(x, xt, K);
    dim3 grid(N / 256, M / 128);  // 43 x 32
    qgemm_dma<<<grid, 512, 0, stream>>>(xt, qweight, qzeros, scales, out, M, N, K);
  } else {
    dim3 grid(N / 128, M / 128);  // 86 x 32
    qgemm_fused<<<grid, 256, 0, stream>>>(x, qweight, qzeros, scales, out, M, N, K);
  }
}